// Round 4
// baseline (216.290 us; speedup 1.0000x reference)
//
#include <hip/hip_runtime.h>

// Quantizer via single-product f16 MFMA screening + certified-margin exact recheck.
//   x: [16,64,32,32] fp32, embed: [64,8192] fp32
//   out[row][c] = embedT[argmax_j (f_row.e_j - ||e_j||^2/2)][c]
//
// R13: screening GEMM switched bf16x3 (6 MFMA/tile, exact-ish) -> f16 single
// product (2 MFMA/tile). R10/R11/R12 proved the 40% MfmaUtil plateau is NOT
// schedule-bound (counted vmcnt, occupancy 2x, full 8-phase: all null) -> cut
// MFMA count 3x instead. Exactness moves to a RIGOROUS per-row margin:
//   |s_f16 - s_exact| <= 2^-10*1.001*||f||*||e|| + 4e-3  (RNE f16, fp32 accum)
//   M_row = 2^-9*1.01*||f_row||*max_j||e_j|| + 4e-3
// rows with quad-gap < M_row are exactly re-scored, but only over chunks with
// pb1[ch] >= b1 - M (any true winner must live there) via a (row,chunk) queue.

typedef _Float16 f16;
typedef __attribute__((ext_vector_type(8))) _Float16 f16x8;
typedef __attribute__((ext_vector_type(4))) float f32x4;
typedef unsigned int u32;
typedef unsigned long long u64;

#define N_ROWS  16384
#define E_DIM   64
#define N_EMBED 8192
#define NCHUNK  16
#define COLS_PER_BLOCK (N_EMBED / NCHUNK)   // 512
#define N_ST (COLS_PER_BLOCK / 64)          // 8 stages of 64 codes
#define ROWS_PER_BLOCK 512                  // 4 waves x 128 pixels
#define N_ROWBLK (N_ROWS / ROWS_PER_BLOCK)  // 32
#define NT 8                                // pixel-tiles per wave

// ---- workspace byte offsets (~9.7 MB total, under prior 11.87 MB footprint)
#define WS_AH   0u                          // pixel f16 [16384][64] (2 MB)
#define WS_B    (2u << 20)                  // codes f16: 128 groups x 8 KB (1 MB)
#define WS_ET   (3u << 20)                  // embedT fp32 [8192][64] (2 MB)
#define WS_BIAS (5u << 20)                  // -||e_j||^2/2 (32 KB)
#define WS_CNT  (WS_BIAS + (32u << 10))     // [0]=nflag [1]=nwork; +16: gn[128]
#define WS_GN   (WS_CNT + 16u)
#define WS_PB1  (WS_CNT + (4u << 10))       // 1 MB
#define WS_PI1  (WS_PB1 + (1u << 20))       // 1 MB
#define WS_PB2  (WS_PI1 + (1u << 20))       // 1 MB
#define WS_FLAG (WS_PB2 + (1u << 20))       // 64 KB
#define WS_FKEY (WS_FLAG + (64u << 10))     // 128 KB u64 keys
#define WS_QUEUE (WS_FKEY + (128u << 10))   // 1 MB (262144 entries = worst case)

__device__ __forceinline__ u32 f32_key(float s) {
    u32 u = __float_as_uint(s);
    return (u & 0x80000000u) ? ~u : (u | 0x80000000u);
}

__device__ __forceinline__ void async16(const void* g, void* l) {
    __builtin_amdgcn_global_load_lds(
        (const __attribute__((address_space(1))) void*)g,
        (__attribute__((address_space(3))) void*)l, 16, 0, 0);
}

// ---- K1: prep. Blocks 0..255: x -> A f16 [row][64].
//          Blocks 256..383: embedT fp32, bias, group max||e||^2, swizzled f16 codes.
__global__ __launch_bounds__(256) void prep(
        const float* __restrict__ x, const float* __restrict__ embed, char* ws) {
    __shared__ float tile[64][65];
    f16* Ah = (f16*)(ws + WS_AH);
    float*  eT = (float*)(ws + WS_ET);
    float*  bias = (float*)(ws + WS_BIAS);
    float*  gn = (float*)(ws + WS_GN);
    const int t = threadIdx.x;
    const int blk = blockIdx.x;

    if (blk < 256) {
        const int b = blk >> 4, p0 = (blk & 15) * 64;
        {
            const int c = t >> 2, seg = (t & 3) * 16;
            const float* src = x + b * 65536 + c * 1024 + p0 + seg;
#pragma unroll
            for (int i = 0; i < 16; ++i) tile[c][seg + i] = src[i];
        }
        __syncthreads();
        const int p = t >> 2, cq = (t & 3) * 16;
        const long row = b * 1024 + p0 + p;
        f16x8 v0, v1;
#pragma unroll
        for (int i = 0; i < 16; ++i) {
            float f = tile[cq + i][p];
            if (i < 8) v0[i] = (f16)f;
            else       v1[i - 8] = (f16)f;
        }
        *(f16x8*)(Ah + row * 64 + cq) = v0;
        *(f16x8*)(Ah + row * 64 + cq + 8) = v1;
    } else {
        if (blk == 256 && t == 0) {
            ((int*)(ws + WS_CNT))[0] = 0;       // nflag
            ((int*)(ws + WS_CNT))[1] = 0;       // nwork
        }
        const int g = blk - 256;             // 64-code group
        const int jbase = g * 64;
        f16* Bg = (f16*)(ws + WS_B) + (size_t)g * 4096;   // 64 codes x 64 f16
        {
            const int c = t >> 2, seg = (t & 3) * 16;
            const float* src = embed + c * N_EMBED + jbase + seg;
#pragma unroll
            for (int i = 0; i < 16; ++i) tile[c][seg + i] = src[i];
        }
        __syncthreads();
        if (t < 64) {
            float s = 0.f;
#pragma unroll
            for (int c = 0; c < 64; ++c) { float v = tile[c][t]; s = fmaf(v, v, s); }
            bias[jbase + t] = -0.5f * s;
            // group max of ||e||^2 (wave 0 butterfly), for the certified margin
            float m = s;
#pragma unroll
            for (int off = 1; off < 64; off <<= 1) m = fmaxf(m, __shfl_xor(m, off));
            if (t == 0) gn[g] = m;
        }
        const int jl = t >> 2, cq = (t & 3) * 16;   // channels cq..cq+15
        f16x8 v0, v1;
#pragma unroll
        for (int i = 0; i < 16; ++i) {
            float f = tile[cq + i][jl];
            eT[(long)(jbase + jl) * 64 + cq + i] = f;
            if (i < 8) v0[i] = (f16)f;
            else       v1[i - 8] = (f16)f;
        }
        // granule-XOR swizzle: logical granule k (8 f16) of code jl stored at
        // position k ^ (jl & 7). Staging stays contiguous, LDS reads conflict-free.
        const int k0 = (cq >> 3), sw = jl & 7;
        f16* hi = Bg + jl * 64;
        *(f16x8*)(hi + ((k0 ^ sw) * 8))       = v0;
        *(f16x8*)(hi + (((k0 + 1) ^ sw) * 8)) = v1;
    }
}

// ---- K2: f16 MFMA GEMM + running (quad-max top-2) argmax.
// grid 512 blocks (32 rowblk x 16 chunks), 256 thr, 2 blocks/CU.
__global__ __launch_bounds__(256, 2) void qdist(const char* __restrict__ ws_c, char* __restrict__ ws) {
    __shared__ __align__(16) char smem[2][8192];
    __shared__ __align__(16) float biasLds[512];
    const f16* Ah = (const f16*)(ws_c + WS_AH);
    const char* Bws = ws_c + WS_B;
    const float* biasg = (const float*)(ws_c + WS_BIAS);
    float* pb1 = (float*)(ws + WS_PB1);
    int*   pi1 = (int*)(ws + WS_PI1);
    float* pb2 = (float*)(ws + WS_PB2);

    const int t = threadIdx.x;
    const int wv = t >> 6, lane = t & 63, ln = lane & 15, q = lane >> 4;
    const int rb = blockIdx.x >> 4, chunk = blockIdx.x & 15;
    const int row0 = rb * ROWS_PER_BLOCK;
    const int col0 = chunk * COLS_PER_BLOCK;
    const int g0 = col0 >> 6;               // first 64-code group of this chunk

    // resident pixel fragments (B-operand): 8 pixel-tiles x 2 K-halves
    f16x8 pf[NT][2];
#pragma unroll
    for (int nt = 0; nt < NT; ++nt) {
        long row = row0 + wv * 128 + nt * 16 + ln;
        long base = row * 64 + q * 8;
        pf[nt][0] = *(const f16x8*)(Ah + base);
        pf[nt][1] = *(const f16x8*)(Ah + base + 32);
    }
    asm volatile("" :
        "+v"(pf[0][0]), "+v"(pf[0][1]), "+v"(pf[1][0]), "+v"(pf[1][1]),
        "+v"(pf[2][0]), "+v"(pf[2][1]), "+v"(pf[3][0]), "+v"(pf[3][1]),
        "+v"(pf[4][0]), "+v"(pf[4][1]), "+v"(pf[5][0]), "+v"(pf[5][1]),
        "+v"(pf[6][0]), "+v"(pf[6][1]), "+v"(pf[7][0]), "+v"(pf[7][1]));

    float b1[NT], b2[NT]; int iq[NT];
#pragma unroll
    for (int k = 0; k < NT; ++k) { b1[k] = -3.4e38f; b2[k] = -3.4e38f; iq[k] = 0; }

    // swizzled fragment read offsets: code cl=ct*16+ln; K-granule q^(ln&7)
    const int s7 = ln & 7;
    const int rdbase = ln * 128 + ((q ^ s7) << 4);

    auto issue = [&](int st) {
        const char* src = Bws + (size_t)(g0 + st) * 8192;
        char* dst = smem[st & 1];
#pragma unroll
        for (int s = 0; s < 2; ++s)
            async16(src + s * 4096 + wv * 1024 + lane * 16,
                    dst + s * 4096 + wv * 1024);
    };

    // prologue: stage chunk bias (2 KB) + first B stage; barrier drains both.
    if (t < 128)
        async16((const char*)(biasg + col0) + t * 16,
                (char*)biasLds + (t >> 6) * 1024);
    issue(0);
    for (int st = 0; st < N_ST; ++st) {
        __syncthreads();                 // own staging drained (vmcnt0 before barrier);
        if (st + 1 < N_ST) issue(st + 1);// all waves done reading buf[(st+1)&1]
        const char* buf = smem[st & 1];
        __builtin_amdgcn_s_setprio(1);
#pragma unroll
        for (int ct = 0; ct < 4; ++ct) {
            const int boff = ct * 2048 + rdbase;
            f16x8 ah0 = *(const f16x8*)(buf + boff);
            f16x8 ah1 = *(const f16x8*)(buf + (boff ^ 64));
            f32x4 bv = *(const f32x4*)(biasLds + st * 64 + ct * 16 + q * 4);
            const int jq = col0 + st * 64 + ct * 16 + q * 4;
#pragma unroll
            for (int nt = 0; nt < NT; ++nt) {
                f32x4 acc = __builtin_amdgcn_mfma_f32_16x16x32_f16(ah0, pf[nt][0], bv, 0, 0, 0);
                acc = __builtin_amdgcn_mfma_f32_16x16x32_f16(ah1, pf[nt][1], acc, 0, 0, 0);
                // quad max (4 codes of one pixel)
                float mx = fmaxf(fmaxf(acc[0], acc[1]), fmaxf(acc[2], acc[3]));
                b2[nt] = fmaxf(b2[nt], fminf(b1[nt], mx));
                bool gt = mx > b1[nt];
                b1[nt] = fmaxf(b1[nt], mx);
                iq[nt] = gt ? jq : iq[nt];
            }
        }
        __builtin_amdgcn_s_setprio(0);
    }

    // merge across the 4 quads (same pixel lives in lanes ln, ln+16, ln+32, ln+48)
#pragma unroll
    for (int m = 16; m < 64; m <<= 1) {
#pragma unroll
        for (int nt = 0; nt < NT; ++nt) {
            float o1 = __shfl_xor(b1[nt], m);
            int   oi = __shfl_xor(iq[nt], m);
            float o2 = __shfl_xor(b2[nt], m);
            b2[nt] = fmaxf(fmaxf(fminf(b1[nt], o1), o2), b2[nt]);
            bool take = (o1 > b1[nt]) || (o1 == b1[nt] && oi < iq[nt]);
            if (take) { b1[nt] = o1; iq[nt] = oi; }
        }
    }
    if (q == 0) {
#pragma unroll
        for (int nt = 0; nt < NT; ++nt) {
            int pixel = row0 + wv * 128 + nt * 16 + ln;
            int o = chunk * N_ROWS + pixel;
            pb1[o] = b1[nt];
            pi1[o] = iq[nt];
            pb2[o] = b2[nt];
        }
    }
}

// ---- K3: merge chunks; certified margin; confident rows -> exact quad pick +
//          direct out write; near-ties -> flag + enqueue candidate chunks.
__global__ __launch_bounds__(64) void reduce_rows(const float* __restrict__ x, char* ws,
                                                  float* __restrict__ out) {
    const float* pb1 = (const float*)(ws + WS_PB1);
    const int*   pi1 = (const int*)(ws + WS_PI1);
    const float* pb2 = (const float*)(ws + WS_PB2);
    const float* eT = (const float*)(ws + WS_ET);
    const float* bias = (const float*)(ws + WS_BIAS);
    const float* gn = (const float*)(ws + WS_GN);
    int* flags = (int*)(ws + WS_FLAG);
    int* cnt = (int*)(ws + WS_CNT);
    u64* fkey = (u64*)(ws + WS_FKEY);
    u32* queue = (u32*)(ws + WS_QUEUE);
    const int row = blockIdx.x * 64 + threadIdx.x;

    float b1 = pb1[row]; int iq = pi1[row]; float b2 = pb2[row];
#pragma unroll
    for (int ch = 1; ch < NCHUNK; ++ch) {
        float o1 = pb1[ch * N_ROWS + row];
        int   oi = pi1[ch * N_ROWS + row];
        float o2 = pb2[ch * N_ROWS + row];
        b2 = fmaxf(fmaxf(fminf(b1, o1), o2), b2);
        if (o1 > b1 || (o1 == b1 && oi < iq)) { b1 = o1; iq = oi; }
    }

    // exact row + ||f||^2 (needed for both paths)
    float xr[64];
    const float* xb = x + (row >> 10) * 65536 + (row & 1023);
#pragma unroll
    for (int c = 0; c < 64; ++c) xr[c] = xb[c * 1024];
    float f2 = 0.f;
#pragma unroll
    for (int c = 0; c < 64; ++c) f2 = fmaf(xr[c], xr[c], f2);
    // max_j ||e_j||^2 over the 128 group maxima
    float e2 = 0.f;
#pragma unroll
    for (int i = 0; i < 32; ++i) {
        f32x4 v = ((const f32x4*)gn)[i];
        e2 = fmaxf(e2, fmaxf(fmaxf(v[0], v[1]), fmaxf(v[2], v[3])));
    }
    // certified margin: 2 * (2^-10 * 1.001 * ||f||*||e||) + abs slack
    const float M = 1.01f * ldexpf(sqrtf(f2) * sqrtf(e2), -9) + 4e-3f;

    if (b1 - b2 < M) {
        fkey[row] = 0ull;                     // any finite score key > 0
        flags[atomicAdd(&cnt[0], 1)] = row;   // out fixed up by gather_fix
        // any code whose TRUE score could win has approx >= b1 - M, hence lives
        // in a chunk with chunk-b1 >= b1 - M. Enqueue those (winning chunk incl.)
#pragma unroll
        for (int ch = 0; ch < NCHUNK; ++ch) {
            if (pb1[ch * N_ROWS + row] >= b1 - M) {
                int p = atomicAdd(&cnt[1], 1);
                queue[p] = ((u32)row << 4) | (u32)ch;
            }
        }
    } else {
        // winning quad certain; exact fp32 argmax within it (codes iq..iq+3)
        float best = -3.4e38f; int bi = iq;
#pragma unroll
        for (int cc = 0; cc < 4; ++cc) {
            const int j = iq + cc;
            const float* e = eT + j * 64;
            float s = bias[j];
#pragma unroll
            for (int c = 0; c < 64; ++c) s = fmaf(xr[c], e[c], s);
            if (s > best) { best = s; bi = j; }   // strict >, ascending j
        }
        const f32x4* src = (const f32x4*)(eT + (size_t)bi * 64);
        f32x4* dst = (f32x4*)(out + (size_t)row * 64);
#pragma unroll
        for (int v = 0; v < 16; ++v) dst[v] = src[v];
    }
}

// ---- K4: exact fp32 rescore of queued (row, chunk) pairs.
// One block per queue entry (grid-stride); 256 thr x 2 codes = 512-code chunk.
__global__ __launch_bounds__(256) void recheck(const float* __restrict__ x, char* ws) {
    __shared__ float fl[64];
    __shared__ u64 red[256];
    const float* eT = (const float*)(ws + WS_ET);
    const float* bias = (const float*)(ws + WS_BIAS);
    const u32* queue = (const u32*)(ws + WS_QUEUE);
    const int nwork = ((const int*)(ws + WS_CNT))[1];
    u64* fkey = (u64*)(ws + WS_FKEY);
    const int t = threadIdx.x;

    for (int w = blockIdx.x; w < nwork; w += gridDim.x) {
        const u32 en = queue[w];
        const int row = (int)(en >> 4), ch = (int)(en & 15u);
        __syncthreads();
        if (t < 64) fl[t] = x[(row >> 10) * 65536 + t * 1024 + (row & 1023)];
        __syncthreads();
        float xr[64];
#pragma unroll
        for (int c = 0; c < 64; ++c) xr[c] = fl[c];

        u64 best = 0ull;
#pragma unroll
        for (int half = 0; half < 2; ++half) {
            const int j = ch * 512 + half * 256 + t;
            const f32x4* e = (const f32x4*)(eT + (size_t)j * 64);
            f32x4 a0 = {0.f, 0.f, 0.f, 0.f}, a1 = a0, a2 = a0, a3 = a0;
#pragma unroll
            for (int v = 0; v < 4; ++v) {
                f32x4 e0 = e[v * 4 + 0], e1 = e[v * 4 + 1];
                f32x4 e2 = e[v * 4 + 2], e3 = e[v * 4 + 3];
#pragma unroll
                for (int k = 0; k < 4; ++k) {
                    a0[k] = fmaf(xr[v * 16 + k],      e0[k], a0[k]);
                    a1[k] = fmaf(xr[v * 16 + 4 + k],  e1[k], a1[k]);
                    a2[k] = fmaf(xr[v * 16 + 8 + k],  e2[k], a2[k]);
                    a3[k] = fmaf(xr[v * 16 + 12 + k], e3[k], a3[k]);
                }
            }
            f32x4 a01 = a0 + a1, a23 = a2 + a3;
            f32x4 as = a01 + a23;
            float s = bias[j] + ((as[0] + as[1]) + (as[2] + as[3]));
            u64 k = ((u64)f32_key(s) << 32) | (u32)(~(u32)j);
            best = (k > best) ? k : best;
        }
        red[t] = best;
        __syncthreads();
        for (int off = 128; off; off >>= 1) {
            if (t < off) { u64 o = red[t + off]; if (o > red[t]) red[t] = o; }
            __syncthreads();
        }
        if (t == 0) atomicMax(&fkey[row], red[0]);
        __syncthreads();
    }
}

// ---- K5: fixup output for flagged rows only (decode winner from fkey)
__global__ __launch_bounds__(256) void gather_fix(const char* __restrict__ ws,
                                                  float* __restrict__ out) {
    const int n = *(const int*)(ws + WS_CNT);
    const int* flags = (const int*)(ws + WS_FLAG);
    const u64* fkey = (const u64*)(ws + WS_FKEY);
    const float* eT = (const float*)(ws + WS_ET);
    const int sub = threadIdx.x >> 6, c = threadIdx.x & 63;
    for (int i = blockIdx.x * 4 + sub; i < n; i += gridDim.x * 4) {
        const int row = flags[i];
        const int idx = (int)(~(u32)(fkey[row] & 0xffffffffull));
        out[(size_t)row * 64 + c] = eT[(size_t)idx * 64 + c];
    }
}

extern "C" void kernel_launch(void* const* d_in, const int* in_sizes, int n_in,
                              void* d_out, int out_size, void* d_ws, size_t ws_size,
                              hipStream_t stream) {
    const float* x     = (const float*)d_in[0];
    const float* embed = (const float*)d_in[1];
    float* out = (float*)d_out;
    char* ws = (char*)d_ws;

    prep<<<384, 256, 0, stream>>>(x, embed, ws);
    qdist<<<N_ROWBLK * NCHUNK, 256, 0, stream>>>(ws, ws);
    reduce_rows<<<N_ROWS / 64, 64, 0, stream>>>(x, ws, out);
    recheck<<<1024, 256, 0, stream>>>(x, ws);
    gather_fix<<<64, 256, 0, stream>>>(ws, out);
}